// Round 11
// baseline (267.403 us; speedup 1.0000x reference)
//
#include <hip/hip_runtime.h>
#include <hip/hip_bf16.h>

// Problem constants (B,S,E,H fixed by the reference)
#define BB 2
#define SS 2048
#define EE 1024
#define HH 16
#define DHH 64

using bf16x8 = __attribute__((ext_vector_type(8))) __bf16;
using f32x4  = __attribute__((ext_vector_type(4))) float;

#if __has_builtin(__builtin_amdgcn_exp2f)
#define EXP2(x) __builtin_amdgcn_exp2f(x)
#else
#define EXP2(x) __exp2f(x)
#endif

static __device__ __forceinline__ unsigned short f2bf(float f) {
    unsigned int u = __float_as_uint(f);
    u += 0x7FFFu + ((u >> 16) & 1u);   // round-to-nearest-even
    return (unsigned short)(u >> 16);
}

// pack two fp32 -> two bf16 in one uint (v_cvt_pk_bf16_f32 on gfx950)
static __device__ __forceinline__ unsigned int pk2bf(float lo, float hi) {
    union { __hip_bfloat162 h2; unsigned int u; } c;
    c.h2 = __float22bfloat162_rn(float2{lo, hi});
    return c.u;
}

// async global->LDS, 16B per lane; LDS dest = wave-uniform base + lane*16
static __device__ __forceinline__ void async_load16(const void* g, void* l) {
    __builtin_amdgcn_global_load_lds(
        (const __attribute__((address_space(1))) unsigned int*)g,
        (__attribute__((address_space(3))) unsigned int*)l, 16, 0, 0);
}

// ---------------------------------------------------------------------------
// fp32 -> bf16 bulk conversion, one fused launch.
// z 0..3: weights (1024^2, 512 x-blocks) into contiguous Wb.
// z 4..6: activations (4096x1024, 2048 x-blocks) into D0/D1/D2.
// ---------------------------------------------------------------------------
__global__ void cvt_kernel(const float* __restrict__ W0, const float* __restrict__ W1,
                           const float* __restrict__ W2, const float* __restrict__ W3,
                           const float* __restrict__ X0, const float* __restrict__ X1,
                           const float* __restrict__ X2,
                           unsigned short* __restrict__ Wb,
                           unsigned short* __restrict__ D0, unsigned short* __restrict__ D1,
                           unsigned short* __restrict__ D2)
{
    const int z = blockIdx.y;
    const float* src;
    unsigned short* dst;
    if (z < 4) {
        if (blockIdx.x >= 512) return;
        src = (z == 0) ? W0 : (z == 1) ? W1 : (z == 2) ? W2 : W3;
        dst = Wb + (size_t)z * 1048576;
    } else {
        src = (z == 4) ? X0 : (z == 5) ? X1 : X2;
        dst = (z == 4) ? D0 : (z == 5) ? D1 : D2;
    }
    const size_t base = (size_t)blockIdx.x * 2048 + (size_t)threadIdx.x * 8;
    const float4 f0 = *(const float4*)(src + base);
    const float4 f1 = *(const float4*)(src + base + 4);
    uint4 p;
    p.x = pk2bf(f0.x, f0.y); p.y = pk2bf(f0.z, f0.w);
    p.z = pk2bf(f1.x, f1.y); p.w = pk2bf(f1.z, f1.w);
    *(uint4*)(dst + base) = p;
}

// ---------------------------------------------------------------------------
// GEMM: Y[m][n] = sum_k A[m][k] * W[n][k]  (X @ W^T).
// Double-buffered LDS + cross-iteration global_load_lds prefetch, one
// barrier per K-iter. MT x NT tile, BK=32, 256 threads (4 waves, 2x2).
// BF16OUT: Y bf16 scaled by per-z ysc. VT_Z2: z==2 writes Y transposed
// per (b, col): Vt[(b*EE+col)*SS + s]. else: Y fp32 + bias.
// ---------------------------------------------------------------------------
template<int MT, int NT, bool BF16OUT, bool VT_Z2>
__global__ __launch_bounds__(256, 3)
void gemm_xwt(const unsigned short* __restrict__ X0, const unsigned short* __restrict__ X1,
              const unsigned short* __restrict__ X2,
              const unsigned short* __restrict__ W0, const unsigned short* __restrict__ W1,
              const unsigned short* __restrict__ W2,
              void* __restrict__ Y0, void* __restrict__ Y1, void* __restrict__ Y2,
              const float* __restrict__ bias, int M, int N, int K,
              float s0, float s1, float s2)
{
    constexpr int BK = 32;
    constexpr int NI = MT / 32;          // A-frags per wave
    constexpr int NJ = NT / 32;          // B-frags per wave
    // UNPADDED: required by global_load_lds (wave-uniform base + lane*16)
    __shared__ __align__(16) unsigned short As[2][MT * BK];
    __shared__ __align__(16) unsigned short Bs[2][NT * BK];

    const int z = blockIdx.z;
    const unsigned short* __restrict__ X = (z == 0) ? X0 : ((z == 1) ? X1 : X2);
    const unsigned short* __restrict__ W = (z == 0) ? W0 : ((z == 1) ? W1 : W2);
    void* __restrict__ Y                 = (z == 0) ? Y0 : ((z == 1) ? Y1 : Y2);
    const float ysc                      = (z == 0) ? s0 : ((z == 1) ? s1 : s2);

    const int tid  = threadIdx.x;
    const int lane = tid & 63;
    const int wave = tid >> 6;
    const int wm   = (wave >> 1) * (MT / 2);
    const int wn   = (wave & 1) * (NT / 2);
    const int m0   = blockIdx.y * MT;
    const int n0   = blockIdx.x * NT;
    const int l16  = lane & 15;
    const int quad = lane >> 4;

    // async staging: lane i covers row (i>>2), k-chunk (i&3)*8 in a 16-row group
    const int arow = lane >> 2;
    const int akc  = (lane & 3) * 8;

    f32x4 acc[NI][NJ];
    #pragma unroll
    for (int i = 0; i < NI; i++)
        #pragma unroll
        for (int j = 0; j < NJ; j++) acc[i][j] = f32x4{0.f, 0.f, 0.f, 0.f};

    auto stage = [&](int k0, int buf) {
        #pragma unroll
        for (int j = 0; j < NT / 64; j++) {
            const int rr = wave * (NT / 4) + j * 16;
            async_load16(W + (size_t)(n0 + rr + arow) * K + k0 + akc, Bs[buf] + rr * BK);
        }
        #pragma unroll
        for (int j = 0; j < MT / 64; j++) {
            const int rr = wave * (MT / 4) + j * 16;
            async_load16(X + (size_t)(m0 + rr + arow) * K + k0 + akc, As[buf] + rr * BK);
        }
    };

    stage(0, 0);                          // prologue: tile 0 -> buf 0
    const int niter = K / BK;
    for (int i = 0; i < niter; i++) {
        const int cur = i & 1;
        __syncthreads();                  // drains tile-i asyncs (issued 1 phase ago)
        if (i + 1 < niter) stage((i + 1) * BK, cur ^ 1);

        bf16x8 afrag[NI], bfrag[NJ];
        #pragma unroll
        for (int ii = 0; ii < NI; ii++)
            afrag[ii] = *(const bf16x8*)(As[cur] + (wm + ii * 16 + l16) * BK + quad * 8);
        #pragma unroll
        for (int j = 0; j < NJ; j++)
            bfrag[j] = *(const bf16x8*)(Bs[cur] + (wn + j * 16 + l16) * BK + quad * 8);
        #pragma unroll
        for (int ii = 0; ii < NI; ii++)
            #pragma unroll
            for (int j = 0; j < NJ; j++)
                acc[ii][j] = __builtin_amdgcn_mfma_f32_16x16x32_bf16(afrag[ii], bfrag[j], acc[ii][j], 0, 0, 0);
    }

    // Epilogue. C/D layout: col = lane&15, row = quad*4 + reg.
    if (BF16OUT && VT_Z2 && z == 2) {
        // transposed per-head store: Vt[(b*EE + col)*SS + s], 4 consecutive s packed
        #pragma unroll
        for (int i = 0; i < NI; i++) {
            const int row0 = m0 + wm + i * 16 + quad * 4;
            const int bb   = row0 >> 11;       // row / SS
            const int sx   = row0 & (SS - 1);
            #pragma unroll
            for (int j = 0; j < NJ; j++) {
                const int col = n0 + wn + j * 16 + l16;
                uint2 pck;
                pck.x = pk2bf(acc[i][j][0], acc[i][j][1]);
                pck.y = pk2bf(acc[i][j][2], acc[i][j][3]);
                *(uint2*)((unsigned short*)Y + (size_t)(bb * EE + col) * SS + sx) = pck;
            }
        }
    } else {
        #pragma unroll
        for (int i = 0; i < NI; i++) {
            #pragma unroll
            for (int j = 0; j < NJ; j++) {
                #pragma unroll
                for (int r = 0; r < 4; r++) {
                    const int row = m0 + wm + i * 16 + quad * 4 + r;
                    const int col = n0 + wn + j * 16 + l16;
                    const float v = acc[i][j][r];
                    if (BF16OUT) {
                        ((unsigned short*)Y)[(size_t)row * N + col] = f2bf(v * ysc);
                    } else {
                        ((float*)Y)[(size_t)row * N + col] = v + bias[col];
                    }
                }
            }
        }
    }
}

// ---------------------------------------------------------------------------
// Flash attention v9 = R9's proven skeleton (256 thr, 4 waves x 32 q,
// mask-as-C-init, exp2 softmax, register prefetch) +
//   (a) XCD swizzle (validated R10: FETCH 69.7->12.3 MB): 1-D grid 512,
//       bh = (linear&7) + 8*((linear>>3)&3), qblk = linear>>5 -> all 16
//       q-blocks of one (b,h) on one XCD; 4 bh/XCD = 2MB K+V < 4MB L2.
//   (b) K-tile 128 (halves barrier crossings; 64 MFMA/wave-iter).
// LDS ~68.5KB -> 2 blocks/CU. Prefetch 8x uint4 = 32 VGPR; bounds (256,2)
// cap 256 -> no spill (R8 lesson checked).
// Vt[(b*EE + h*64 + d)*SS + s]. AO bf16.
// ---------------------------------------------------------------------------
__global__ __launch_bounds__(256, 2)
void attn_kernel(const unsigned short* __restrict__ Qb,
                 const unsigned short* __restrict__ Kb,
                 const unsigned short* __restrict__ Vt,
                 const int* __restrict__ mask,
                 unsigned short* __restrict__ AO)
{
    constexpr int TK  = 128; // keys per tile
    constexpr int LDK = 68;  // [key][d] stride: conflict-free (measured 0, R4-R9)
    constexpr int LDV = 136; // [d][key] stride: 272B, 16B-aligned; worst 2-way (free)
    constexpr int LDP = 136;
    __shared__ __align__(16) unsigned short Ks[TK * LDK];       // [key][d]
    __shared__ __align__(16) unsigned short Vs[64 * LDV];       // [d][key]
    __shared__ __align__(16) unsigned short Ps[4 * 32 * LDP];   // per-wave [q(32)][key]
    __shared__ __align__(16) float Msf[TK];                     // mask bias (0 / -150)

    const int tid  = threadIdx.x;
    const int lane = tid & 63;
    const int wave = tid >> 6;
    const int l16  = lane & 15;
    const int quad = lane >> 4;

    // XCD-aware decode (see header comment)
    const int linear = blockIdx.x;
    const int bh     = (linear & 7) + 8 * ((linear >> 3) & 3);
    const int qblk   = linear >> 5;
    const int b  = bh >> 4;
    const int h  = bh & 15;
    const int q0 = qblk * 128 + wave * 32;

    // Q fragments, 2 groups of 16 q (B-operand: lane n=q=l16, k=d=quad*8+j).
    // Pre-scaled by log2e/sqrt(S) in the projection GEMM.
    bf16x8 qf[2][2];
    #pragma unroll
    for (int g = 0; g < 2; g++) {
        const unsigned short* qptr = Qb + (size_t)(b * SS + q0 + g * 16 + l16) * EE + h * DHH;
        qf[g][0] = *(const bf16x8*)(qptr + quad * 8);
        qf[g][1] = *(const bf16x8*)(qptr + 32 + quad * 8);
    }

    float lsum[2] = {0.f, 0.f};
    f32x4 o_acc[2][4];
    #pragma unroll
    for (int g = 0; g < 2; g++)
        #pragma unroll
        for (int j = 0; j < 4; j++) o_acc[g][j] = f32x4{0.f, 0.f, 0.f, 0.f};

    unsigned short* Pw = Ps + wave * 32 * LDP;

    // K staging: 2 threads per key row (128 rows), 64B each
    const int krow = tid >> 1;          // 0..127
    const int kc   = (tid & 1) * 32;    // d-elem offset 0 or 32
    // V staging: 4 threads per d row (64 rows), 64B each
    const int vrow = tid >> 2;          // 0..63
    const int vc   = (tid & 3) * 32;    // key-elem offset 0,32,64,96

    // ---- register prefetch state (tile t+1 lives here during compute of t)
    uint4 kr[4], vr[4];
    int   mr = 0;
    auto gload = [&](int t0) {
        const unsigned short* kg = Kb + (size_t)(b * SS + t0 + krow) * EE + h * DHH + kc;
        const unsigned short* vg = Vt + (size_t)(b * EE + h * DHH + vrow) * SS + t0 + vc;
        #pragma unroll
        for (int j = 0; j < 4; j++) {
            kr[j] = *(const uint4*)(kg + j * 8);
            vr[j] = *(const uint4*)(vg + j * 8);
        }
        if (tid < TK) mr = mask[b * SS + t0 + tid];
    };
    gload(0);

    for (int t0 = 0; t0 < SS; t0 += TK) {
        __syncthreads();   // prior iteration's Ks/Vs frag reads done
        #pragma unroll
        for (int j = 0; j < 4; j++) {
            *(uint4*)(Ks + krow * LDK + kc + j * 8) = kr[j];
            *(uint4*)(Vs + vrow * LDV + vc + j * 8) = vr[j];
        }
        if (tid < TK) Msf[tid] = mr ? 0.0f : -150.0f;
        __syncthreads();

        // prefetch next tile into registers, overlapped with compute below
        if (t0 + TK < SS) gload(t0 + TK);

        // S^T tile (128 keys x 32 q): mask bias as MFMA C-init, p = exp2(score).
        // Each kf read feeds both q-groups.
        #pragma unroll
        for (int nt = 0; nt < 8; nt++) {
            bf16x8 kf0 = *(const bf16x8*)(Ks + (nt * 16 + l16) * LDK + quad * 8);
            bf16x8 kf1 = *(const bf16x8*)(Ks + (nt * 16 + l16) * LDK + 32 + quad * 8);
            const f32x4 cinit = *(const f32x4*)(Msf + nt * 16 + quad * 4);
            #pragma unroll
            for (int g = 0; g < 2; g++) {
                f32x4 a = __builtin_amdgcn_mfma_f32_16x16x32_bf16(kf0, qf[g][0], cinit, 0, 0, 0);
                a = __builtin_amdgcn_mfma_f32_16x16x32_bf16(kf1, qf[g][1], a, 0, 0, 0);
                const float p0 = EXP2(a[0]);
                const float p1 = EXP2(a[1]);
                const float p2 = EXP2(a[2]);
                const float p3 = EXP2(a[3]);
                lsum[g] += (p0 + p1) + (p2 + p3);
                uint2 pck;
                pck.x = pk2bf(p0, p1);
                pck.y = pk2bf(p2, p3);
                *(uint2*)(Pw + (g * 16 + l16) * LDP + nt * 16 + quad * 4) = pck;
            }
        }

        // wave-local: ensure P writes land before P frag reads (no barrier)
        __builtin_amdgcn_s_waitcnt(0xC07F);   // lgkmcnt(0)

        // O^T += V^T . P  — each vf read feeds both q-groups
        #pragma unroll
        for (int s2 = 0; s2 < 4; s2++) {
            bf16x8 pf0 = *(const bf16x8*)(Pw + l16 * LDP + s2 * 32 + quad * 8);
            bf16x8 pf1 = *(const bf16x8*)(Pw + (16 + l16) * LDP + s2 * 32 + quad * 8);
            #pragma unroll
            for (int jg = 0; jg < 4; jg++) {
                bf16x8 vf = *(const bf16x8*)(Vs + (jg * 16 + l16) * LDV + s2 * 32 + quad * 8);
                o_acc[0][jg] = __builtin_amdgcn_mfma_f32_16x16x32_bf16(vf, pf0, o_acc[0][jg], 0, 0, 0);
                o_acc[1][jg] = __builtin_amdgcn_mfma_f32_16x16x32_bf16(vf, pf1, o_acc[1][jg], 0, 0, 0);
            }
        }
    }

    // final l reduction + store, per q-group
    #pragma unroll
    for (int g = 0; g < 2; g++) {
        float ls = lsum[g];
        ls += __shfl_xor(ls, 16, 64);
        ls += __shfl_xor(ls, 32, 64);
        const float rl = 1.0f / ls;
        const size_t orow = (size_t)(b * SS + q0 + g * 16 + l16) * EE + h * DHH;
        #pragma unroll
        for (int jg = 0; jg < 4; jg++) {
            uint2 pck;
            pck.x = pk2bf(o_acc[g][jg][0] * rl, o_acc[g][jg][1] * rl);
            pck.y = pk2bf(o_acc[g][jg][2] * rl, o_acc[g][jg][3] * rl);
            *(uint2*)(AO + orow + jg * 16 + quad * 4) = pck;
        }
    }
}

// ---------------------------------------------------------------------------
// Workspace/d_out aliasing plan (stream order makes every alias race-free):
//   d_out (16 MB): [Xq bf16 8MB | Xk bf16 8MB]  -- dead once proj GEMM reads;
//                  final GEMM overwrites d_out with the real output.
//   ws (40 MB):    [Wb 8MB | Xv 8MB | Qb 8MB | Kb 8MB | Vtb 8MB]
//                  AOb aliases Xv (Xv dead once proj GEMM reads it).
// ---------------------------------------------------------------------------
extern "C" void kernel_launch(void* const* d_in, const int* in_sizes, int n_in,
                              void* d_out, int out_size, void* d_ws, size_t ws_size,
                              hipStream_t stream)
{
    (void)in_sizes; (void)n_in; (void)out_size; (void)ws_size;
    const float* queries = (const float*)d_in[0];
    const float* keys    = (const float*)d_in[1];
    const float* values  = (const float*)d_in[2];
    const int*   mask    = (const int*)d_in[3];
    const float* Wq      = (const float*)d_in[4];
    const float* Wk      = (const float*)d_in[5];
    const float* Wv      = (const float*)d_in[6];
    const float* Wo      = (const float*)d_in[7];
    const float* bo      = (const float*)d_in[8];

    const size_t NE = (size_t)BB * SS * EE;          // 4.19M elements
    const size_t WE = (size_t)EE * EE;               // 1.05M elements

    unsigned short* Xq  = (unsigned short*)d_out;    // 8 MB (scratch phase)
    unsigned short* Xk  = Xq + NE;                   // 8 MB (scratch phase)
    unsigned short* Wb  = (unsigned short*)d_ws;     // 8 MB (4 weights bf16)
    unsigned short* Xv  = Wb + 4 * WE;               // 8 MB
    unsigned short* Qb  = Xv + NE;                   // 8 MB (pre-scaled)
    unsigned short* Kb  = Qb + NE;                   // 8 MB
    unsigned short* Vtb = Kb + NE;                   // 8 MB (per-head transposed V)
    unsigned short* AOb = Xv;                        // alias: Xv dead after proj GEMM

    const int M = BB * SS, N = EE, K = EE;
    // 1/sqrt(2048) * log2(e): softmax exp computed as exp2 of pre-scaled score
    const float qscale = 0.022097086912079608f * 1.4426950408889634f;

    cvt_kernel<<<dim3(2048, 7), 256, 0, stream>>>(
        Wq, Wk, Wv, Wo, queries, keys, values, Wb, Xq, Xk, Xv);

    dim3 gproj(N / 128, M / 128, 3);
    gemm_xwt<128, 128, true, true><<<gproj, 256, 0, stream>>>(
        Xq, Xk, Xv, Wb, Wb + WE, Wb + 2 * WE,
        (void*)Qb, (void*)Kb, (void*)Vtb, nullptr, M, N, K,
        qscale, 1.0f, 1.0f);

    attn_kernel<<<dim3((SS / 128) * BB * HH), 256, 0, stream>>>(Qb, Kb, Vtb, mask, AOb);

    dim3 gout(N / 64, M / 64, 1);
    gemm_xwt<64, 64, false, false><<<gout, 256, 0, stream>>>(
        AOb, AOb, AOb, Wb + 3 * WE, Wb + 3 * WE, Wb + 3 * WE,
        d_out, d_out, d_out, bo, M, N, K, 1.0f, 1.0f, 1.0f);
}

// Round 12
// 243.235 us; speedup vs baseline: 1.0994x; 1.0994x over previous
//
#include <hip/hip_runtime.h>
#include <hip/hip_bf16.h>

// Problem constants (B,S,E,H fixed by the reference)
#define BB 2
#define SS 2048
#define EE 1024
#define HH 16
#define DHH 64

using bf16x8 = __attribute__((ext_vector_type(8))) __bf16;
using f32x4  = __attribute__((ext_vector_type(4))) float;

#if __has_builtin(__builtin_amdgcn_exp2f)
#define EXP2(x) __builtin_amdgcn_exp2f(x)
#else
#define EXP2(x) __exp2f(x)
#endif

static __device__ __forceinline__ unsigned short f2bf(float f) {
    unsigned int u = __float_as_uint(f);
    u += 0x7FFFu + ((u >> 16) & 1u);   // round-to-nearest-even
    return (unsigned short)(u >> 16);
}

// pack two fp32 -> two bf16 in one uint (v_cvt_pk_bf16_f32 on gfx950)
static __device__ __forceinline__ unsigned int pk2bf(float lo, float hi) {
    union { __hip_bfloat162 h2; unsigned int u; } c;
    c.h2 = __float22bfloat162_rn(float2{lo, hi});
    return c.u;
}

// async global->LDS, 16B per lane; LDS dest = wave-uniform base + lane*16
static __device__ __forceinline__ void async_load16(const void* g, void* l) {
    __builtin_amdgcn_global_load_lds(
        (const __attribute__((address_space(1))) unsigned int*)g,
        (__attribute__((address_space(3))) unsigned int*)l, 16, 0, 0);
}

// ---------------------------------------------------------------------------
// fp32 -> bf16 bulk conversion, one fused launch.
// z 0..3: weights (1024^2, 512 x-blocks) into contiguous Wb.
// z 4..6: activations (4096x1024, 2048 x-blocks) into D0/D1/D2.
// ---------------------------------------------------------------------------
__global__ void cvt_kernel(const float* __restrict__ W0, const float* __restrict__ W1,
                           const float* __restrict__ W2, const float* __restrict__ W3,
                           const float* __restrict__ X0, const float* __restrict__ X1,
                           const float* __restrict__ X2,
                           unsigned short* __restrict__ Wb,
                           unsigned short* __restrict__ D0, unsigned short* __restrict__ D1,
                           unsigned short* __restrict__ D2)
{
    const int z = blockIdx.y;
    const float* src;
    unsigned short* dst;
    if (z < 4) {
        if (blockIdx.x >= 512) return;
        src = (z == 0) ? W0 : (z == 1) ? W1 : (z == 2) ? W2 : W3;
        dst = Wb + (size_t)z * 1048576;
    } else {
        src = (z == 4) ? X0 : (z == 5) ? X1 : X2;
        dst = (z == 4) ? D0 : (z == 5) ? D1 : D2;
    }
    const size_t base = (size_t)blockIdx.x * 2048 + (size_t)threadIdx.x * 8;
    const float4 f0 = *(const float4*)(src + base);
    const float4 f1 = *(const float4*)(src + base + 4);
    uint4 p;
    p.x = pk2bf(f0.x, f0.y); p.y = pk2bf(f0.z, f0.w);
    p.z = pk2bf(f1.x, f1.y); p.w = pk2bf(f1.z, f1.w);
    *(uint4*)(dst + base) = p;
}

// ---------------------------------------------------------------------------
// GEMM: Y[m][n] = sum_k A[m][k] * W[n][k]  (X @ W^T).
// Double-buffered LDS + cross-iteration global_load_lds prefetch, one
// barrier per K-iter. MT x NT tile, BK=32, 256 threads (4 waves, 2x2).
// BF16OUT: Y bf16 scaled by per-z ysc. VT_Z2: z==2 writes Y transposed
// per (b, col): Vt[(b*EE+col)*SS + s]. else: Y fp32 + bias.
// ---------------------------------------------------------------------------
template<int MT, int NT, bool BF16OUT, bool VT_Z2>
__global__ __launch_bounds__(256, 3)
void gemm_xwt(const unsigned short* __restrict__ X0, const unsigned short* __restrict__ X1,
              const unsigned short* __restrict__ X2,
              const unsigned short* __restrict__ W0, const unsigned short* __restrict__ W1,
              const unsigned short* __restrict__ W2,
              void* __restrict__ Y0, void* __restrict__ Y1, void* __restrict__ Y2,
              const float* __restrict__ bias, int M, int N, int K,
              float s0, float s1, float s2)
{
    constexpr int BK = 32;
    constexpr int NI = MT / 32;          // A-frags per wave
    constexpr int NJ = NT / 32;          // B-frags per wave
    // UNPADDED: required by global_load_lds (wave-uniform base + lane*16)
    __shared__ __align__(16) unsigned short As[2][MT * BK];
    __shared__ __align__(16) unsigned short Bs[2][NT * BK];

    const int z = blockIdx.z;
    const unsigned short* __restrict__ X = (z == 0) ? X0 : ((z == 1) ? X1 : X2);
    const unsigned short* __restrict__ W = (z == 0) ? W0 : ((z == 1) ? W1 : W2);
    void* __restrict__ Y                 = (z == 0) ? Y0 : ((z == 1) ? Y1 : Y2);
    const float ysc                      = (z == 0) ? s0 : ((z == 1) ? s1 : s2);

    const int tid  = threadIdx.x;
    const int lane = tid & 63;
    const int wave = tid >> 6;
    const int wm   = (wave >> 1) * (MT / 2);
    const int wn   = (wave & 1) * (NT / 2);
    const int m0   = blockIdx.y * MT;
    const int n0   = blockIdx.x * NT;
    const int l16  = lane & 15;
    const int quad = lane >> 4;

    // async staging: lane i covers row (i>>2), k-chunk (i&3)*8 in a 16-row group
    const int arow = lane >> 2;
    const int akc  = (lane & 3) * 8;

    f32x4 acc[NI][NJ];
    #pragma unroll
    for (int i = 0; i < NI; i++)
        #pragma unroll
        for (int j = 0; j < NJ; j++) acc[i][j] = f32x4{0.f, 0.f, 0.f, 0.f};

    auto stage = [&](int k0, int buf) {
        #pragma unroll
        for (int j = 0; j < NT / 64; j++) {
            const int rr = wave * (NT / 4) + j * 16;
            async_load16(W + (size_t)(n0 + rr + arow) * K + k0 + akc, Bs[buf] + rr * BK);
        }
        #pragma unroll
        for (int j = 0; j < MT / 64; j++) {
            const int rr = wave * (MT / 4) + j * 16;
            async_load16(X + (size_t)(m0 + rr + arow) * K + k0 + akc, As[buf] + rr * BK);
        }
    };

    stage(0, 0);                          // prologue: tile 0 -> buf 0
    const int niter = K / BK;
    for (int i = 0; i < niter; i++) {
        const int cur = i & 1;
        __syncthreads();                  // drains tile-i asyncs (issued 1 phase ago)
        if (i + 1 < niter) stage((i + 1) * BK, cur ^ 1);

        bf16x8 afrag[NI], bfrag[NJ];
        #pragma unroll
        for (int ii = 0; ii < NI; ii++)
            afrag[ii] = *(const bf16x8*)(As[cur] + (wm + ii * 16 + l16) * BK + quad * 8);
        #pragma unroll
        for (int j = 0; j < NJ; j++)
            bfrag[j] = *(const bf16x8*)(Bs[cur] + (wn + j * 16 + l16) * BK + quad * 8);
        #pragma unroll
        for (int ii = 0; ii < NI; ii++)
            #pragma unroll
            for (int j = 0; j < NJ; j++)
                acc[ii][j] = __builtin_amdgcn_mfma_f32_16x16x32_bf16(afrag[ii], bfrag[j], acc[ii][j], 0, 0, 0);
    }

    // Epilogue. C/D layout: col = lane&15, row = quad*4 + reg.
    if (BF16OUT && VT_Z2 && z == 2) {
        // transposed per-head store: Vt[(b*EE + col)*SS + s], 4 consecutive s packed
        #pragma unroll
        for (int i = 0; i < NI; i++) {
            const int row0 = m0 + wm + i * 16 + quad * 4;
            const int bb   = row0 >> 11;       // row / SS
            const int sx   = row0 & (SS - 1);
            #pragma unroll
            for (int j = 0; j < NJ; j++) {
                const int col = n0 + wn + j * 16 + l16;
                uint2 pck;
                pck.x = pk2bf(acc[i][j][0], acc[i][j][1]);
                pck.y = pk2bf(acc[i][j][2], acc[i][j][3]);
                *(uint2*)((unsigned short*)Y + (size_t)(bb * EE + col) * SS + sx) = pck;
            }
        }
    } else {
        #pragma unroll
        for (int i = 0; i < NI; i++) {
            #pragma unroll
            for (int j = 0; j < NJ; j++) {
                #pragma unroll
                for (int r = 0; r < 4; r++) {
                    const int row = m0 + wm + i * 16 + quad * 4 + r;
                    const int col = n0 + wn + j * 16 + l16;
                    const float v = acc[i][j][r];
                    if (BF16OUT) {
                        ((unsigned short*)Y)[(size_t)row * N + col] = f2bf(v * ysc);
                    } else {
                        ((float*)Y)[(size_t)row * N + col] = v + bias[col];
                    }
                }
            }
        }
    }
}

// ---------------------------------------------------------------------------
// Flash attention v10 = R9's proven skeleton UNCHANGED (256 thr, 4 waves x
// 32 q, K-tile 64, LDK/LDV/LDP=68, mask-as-C-init, exp2 softmax, register
// prefetch 4x uint4, VGPR 80, zero conflicts) + XCD swizzle only
// (validated R10/R11: FETCH 69.7 -> 12-21 MB):
//   1-D grid 512; xcd = linear&7 serves bh in {4*xcd .. 4*xcd+3}
//   (4 heads x 512KB K+V = 2MB < 4MB XCD L2), qblk = linear>>5.
// Vt[(b*EE + h*64 + d)*SS + s]. AO bf16.
// ---------------------------------------------------------------------------
__global__ __launch_bounds__(256, 2)
void attn_kernel(const unsigned short* __restrict__ Qb,
                 const unsigned short* __restrict__ Kb,
                 const unsigned short* __restrict__ Vt,
                 const int* __restrict__ mask,
                 unsigned short* __restrict__ AO)
{
    constexpr int LDK = 68;  // 136B stride: conflict-free (measured 0 in R4-R9)
    constexpr int LDV = 68;
    constexpr int LDP = 68;
    __shared__ __align__(16) unsigned short Ks[64 * LDK];       // [key][d]
    __shared__ __align__(16) unsigned short Vs[64 * LDV];       // [d][key]
    __shared__ __align__(16) unsigned short Ps[4 * 32 * LDP];   // per-wave [q(32)][key]
    __shared__ __align__(16) float Msf[64];                     // mask bias (0 / -150)

    const int tid  = threadIdx.x;
    const int lane = tid & 63;
    const int wave = tid >> 6;
    const int l16  = lane & 15;
    const int quad = lane >> 4;

    // XCD-aware decode: assumes round-robin linear->XCD dispatch (perf-only)
    const int linear = blockIdx.x;
    const int bh     = (linear & 7) * 4 + ((linear >> 3) & 3);
    const int qblk   = linear >> 5;
    const int b  = bh >> 4;
    const int h  = bh & 15;
    const int q0 = qblk * 128 + wave * 32;

    // Q fragments, 2 groups of 16 q (B-operand: lane n=q=l16, k=d=quad*8+j).
    // Pre-scaled by log2e/sqrt(S) in the projection GEMM.
    bf16x8 qf[2][2];
    #pragma unroll
    for (int g = 0; g < 2; g++) {
        const unsigned short* qptr = Qb + (size_t)(b * SS + q0 + g * 16 + l16) * EE + h * DHH;
        qf[g][0] = *(const bf16x8*)(qptr + quad * 8);
        qf[g][1] = *(const bf16x8*)(qptr + 32 + quad * 8);
    }

    float lsum[2] = {0.f, 0.f};
    f32x4 o_acc[2][4];
    #pragma unroll
    for (int g = 0; g < 2; g++)
        #pragma unroll
        for (int j = 0; j < 4; j++) o_acc[g][j] = f32x4{0.f, 0.f, 0.f, 0.f};

    unsigned short* Pw = Ps + wave * 32 * LDP;

    // staging: 4 threads per row, 32B each
    const int srow = tid >> 2;          // 0..63
    const int sc   = (tid & 3) * 16;    // elem offset 0,16,32,48

    // ---- register prefetch state (tile t+1 lives here during compute of t)
    uint4 kr0, kr1, vr0, vr1;
    int   mr = 0;
    auto gload = [&](int t0) {
        const unsigned short* kg = Kb + (size_t)(b * SS + t0 + srow) * EE + h * DHH + sc;
        kr0 = *(const uint4*)(kg);
        kr1 = *(const uint4*)(kg + 8);
        const unsigned short* vg = Vt + (size_t)(b * EE + h * DHH + srow) * SS + t0 + sc;
        vr0 = *(const uint4*)(vg);
        vr1 = *(const uint4*)(vg + 8);
        if (tid < 64) mr = mask[b * SS + t0 + tid];
    };
    gload(0);

    for (int t0 = 0; t0 < SS; t0 += 64) {
        __syncthreads();   // prior iteration's Ks/Vs frag reads done
        *(uint4*)(Ks + srow * LDK + sc)     = kr0;
        *(uint4*)(Ks + srow * LDK + sc + 8) = kr1;
        *(uint4*)(Vs + srow * LDV + sc)     = vr0;
        *(uint4*)(Vs + srow * LDV + sc + 8) = vr1;
        if (tid < 64) Msf[tid] = mr ? 0.0f : -150.0f;
        __syncthreads();

        // prefetch next tile into registers, overlapped with compute below
        if (t0 + 64 < SS) gload(t0 + 64);

        // S^T tile (64 keys x 32 q): mask bias as MFMA C-init, p = exp2(score).
        // Each kf read feeds both q-groups.
        #pragma unroll
        for (int nt = 0; nt < 4; nt++) {
            bf16x8 kf0 = *(const bf16x8*)(Ks + (nt * 16 + l16) * LDK + quad * 8);
            bf16x8 kf1 = *(const bf16x8*)(Ks + (nt * 16 + l16) * LDK + 32 + quad * 8);
            const f32x4 cinit = *(const f32x4*)(Msf + nt * 16 + quad * 4);
            #pragma unroll
            for (int g = 0; g < 2; g++) {
                f32x4 a = __builtin_amdgcn_mfma_f32_16x16x32_bf16(kf0, qf[g][0], cinit, 0, 0, 0);
                a = __builtin_amdgcn_mfma_f32_16x16x32_bf16(kf1, qf[g][1], a, 0, 0, 0);
                const float p0 = EXP2(a[0]);
                const float p1 = EXP2(a[1]);
                const float p2 = EXP2(a[2]);
                const float p3 = EXP2(a[3]);
                lsum[g] += (p0 + p1) + (p2 + p3);
                uint2 pck;
                pck.x = pk2bf(p0, p1);
                pck.y = pk2bf(p2, p3);
                *(uint2*)(Pw + (g * 16 + l16) * LDP + nt * 16 + quad * 4) = pck;
            }
        }

        // wave-local: ensure P writes land before P frag reads (no barrier)
        __builtin_amdgcn_s_waitcnt(0xC07F);   // lgkmcnt(0)

        // O^T += V^T . P  — each vf read feeds both q-groups
        #pragma unroll
        for (int s2 = 0; s2 < 2; s2++) {
            bf16x8 pf0 = *(const bf16x8*)(Pw + l16 * LDP + s2 * 32 + quad * 8);
            bf16x8 pf1 = *(const bf16x8*)(Pw + (16 + l16) * LDP + s2 * 32 + quad * 8);
            #pragma unroll
            for (int jg = 0; jg < 4; jg++) {
                bf16x8 vf = *(const bf16x8*)(Vs + (jg * 16 + l16) * LDV + s2 * 32 + quad * 8);
                o_acc[0][jg] = __builtin_amdgcn_mfma_f32_16x16x32_bf16(vf, pf0, o_acc[0][jg], 0, 0, 0);
                o_acc[1][jg] = __builtin_amdgcn_mfma_f32_16x16x32_bf16(vf, pf1, o_acc[1][jg], 0, 0, 0);
            }
        }
    }

    // final l reduction + store, per q-group
    #pragma unroll
    for (int g = 0; g < 2; g++) {
        float ls = lsum[g];
        ls += __shfl_xor(ls, 16, 64);
        ls += __shfl_xor(ls, 32, 64);
        const float rl = 1.0f / ls;
        const size_t orow = (size_t)(b * SS + q0 + g * 16 + l16) * EE + h * DHH;
        #pragma unroll
        for (int jg = 0; jg < 4; jg++) {
            uint2 pck;
            pck.x = pk2bf(o_acc[g][jg][0] * rl, o_acc[g][jg][1] * rl);
            pck.y = pk2bf(o_acc[g][jg][2] * rl, o_acc[g][jg][3] * rl);
            *(uint2*)(AO + orow + jg * 16 + quad * 4) = pck;
        }
    }
}

// ---------------------------------------------------------------------------
// Workspace/d_out aliasing plan (stream order makes every alias race-free):
//   d_out (16 MB): [Xq bf16 8MB | Xk bf16 8MB]  -- dead once proj GEMM reads;
//                  final GEMM overwrites d_out with the real output.
//   ws (40 MB):    [Wb 8MB | Xv 8MB | Qb 8MB | Kb 8MB | Vtb 8MB]
//                  AOb aliases Xv (Xv dead once proj GEMM reads it).
// ---------------------------------------------------------------------------
extern "C" void kernel_launch(void* const* d_in, const int* in_sizes, int n_in,
                              void* d_out, int out_size, void* d_ws, size_t ws_size,
                              hipStream_t stream)
{
    (void)in_sizes; (void)n_in; (void)out_size; (void)ws_size;
    const float* queries = (const float*)d_in[0];
    const float* keys    = (const float*)d_in[1];
    const float* values  = (const float*)d_in[2];
    const int*   mask    = (const int*)d_in[3];
    const float* Wq      = (const float*)d_in[4];
    const float* Wk      = (const float*)d_in[5];
    const float* Wv      = (const float*)d_in[6];
    const float* Wo      = (const float*)d_in[7];
    const float* bo      = (const float*)d_in[8];

    const size_t NE = (size_t)BB * SS * EE;          // 4.19M elements
    const size_t WE = (size_t)EE * EE;               // 1.05M elements

    unsigned short* Xq  = (unsigned short*)d_out;    // 8 MB (scratch phase)
    unsigned short* Xk  = Xq + NE;                   // 8 MB (scratch phase)
    unsigned short* Wb  = (unsigned short*)d_ws;     // 8 MB (4 weights bf16)
    unsigned short* Xv  = Wb + 4 * WE;               // 8 MB
    unsigned short* Qb  = Xv + NE;                   // 8 MB (pre-scaled)
    unsigned short* Kb  = Qb + NE;                   // 8 MB
    unsigned short* Vtb = Kb + NE;                   // 8 MB (per-head transposed V)
    unsigned short* AOb = Xv;                        // alias: Xv dead after proj GEMM

    const int M = BB * SS, N = EE, K = EE;
    // 1/sqrt(2048) * log2(e): softmax exp computed as exp2 of pre-scaled score
    const float qscale = 0.022097086912079608f * 1.4426950408889634f;

    cvt_kernel<<<dim3(2048, 7), 256, 0, stream>>>(
        Wq, Wk, Wv, Wo, queries, keys, values, Wb, Xq, Xk, Xv);

    dim3 gproj(N / 128, M / 128, 3);
    gemm_xwt<128, 128, true, true><<<gproj, 256, 0, stream>>>(
        Xq, Xk, Xv, Wb, Wb + WE, Wb + 2 * WE,
        (void*)Qb, (void*)Kb, (void*)Vtb, nullptr, M, N, K,
        qscale, 1.0f, 1.0f);

    attn_kernel<<<dim3(512), 256, 0, stream>>>(Qb, Kb, Vtb, mask, AOb);

    dim3 gout(N / 64, M / 64, 1);
    gemm_xwt<64, 64, false, false><<<gout, 256, 0, stream>>>(
        AOb, AOb, AOb, Wb + 3 * WE, Wb + 3 * WE, Wb + 3 * WE,
        d_out, d_out, d_out, bo, M, N, K, 1.0f, 1.0f, 1.0f);
}

// Round 14
// 236.442 us; speedup vs baseline: 1.1309x; 1.0287x over previous
//
#include <hip/hip_runtime.h>
#include <hip/hip_bf16.h>

// Problem constants (B,S,E,H fixed by the reference)
#define BB 2
#define SS 2048
#define EE 1024
#define HH 16
#define DHH 64

using bf16x8 = __attribute__((ext_vector_type(8))) __bf16;
using f32x4  = __attribute__((ext_vector_type(4))) float;

#if __has_builtin(__builtin_amdgcn_exp2f)
#define EXP2(x) __builtin_amdgcn_exp2f(x)
#else
#define EXP2(x) __exp2f(x)
#endif

static __device__ __forceinline__ unsigned short f2bf(float f) {
    unsigned int u = __float_as_uint(f);
    u += 0x7FFFu + ((u >> 16) & 1u);   // round-to-nearest-even
    return (unsigned short)(u >> 16);
}

// pack two fp32 -> two bf16 in one uint (v_cvt_pk_bf16_f32 on gfx950)
static __device__ __forceinline__ unsigned int pk2bf(float lo, float hi) {
    union { __hip_bfloat162 h2; unsigned int u; } c;
    c.h2 = __float22bfloat162_rn(float2{lo, hi});
    return c.u;
}

// async global->LDS, 16B per lane; LDS dest = wave-uniform base + lane*16
static __device__ __forceinline__ void async_load16(const void* g, void* l) {
    __builtin_amdgcn_global_load_lds(
        (const __attribute__((address_space(1))) unsigned int*)g,
        (__attribute__((address_space(3))) unsigned int*)l, 16, 0, 0);
}

// ---------------------------------------------------------------------------
// fp32 -> bf16 bulk conversion, one fused launch.
// z 0..3: weights (1024^2, 512 x-blocks) into contiguous Wb.
// z 4..6: activations (4096x1024, 2048 x-blocks) into D0/D1/D2.
// ---------------------------------------------------------------------------
__global__ void cvt_kernel(const float* __restrict__ W0, const float* __restrict__ W1,
                           const float* __restrict__ W2, const float* __restrict__ W3,
                           const float* __restrict__ X0, const float* __restrict__ X1,
                           const float* __restrict__ X2,
                           unsigned short* __restrict__ Wb,
                           unsigned short* __restrict__ D0, unsigned short* __restrict__ D1,
                           unsigned short* __restrict__ D2)
{
    const int z = blockIdx.y;
    const float* src;
    unsigned short* dst;
    if (z < 4) {
        if (blockIdx.x >= 512) return;
        src = (z == 0) ? W0 : (z == 1) ? W1 : (z == 2) ? W2 : W3;
        dst = Wb + (size_t)z * 1048576;
    } else {
        src = (z == 4) ? X0 : (z == 5) ? X1 : X2;
        dst = (z == 4) ? D0 : (z == 5) ? D1 : D2;
    }
    const size_t base = (size_t)blockIdx.x * 2048 + (size_t)threadIdx.x * 8;
    const float4 f0 = *(const float4*)(src + base);
    const float4 f1 = *(const float4*)(src + base + 4);
    uint4 p;
    p.x = pk2bf(f0.x, f0.y); p.y = pk2bf(f0.z, f0.w);
    p.z = pk2bf(f1.x, f1.y); p.w = pk2bf(f1.z, f1.w);
    *(uint4*)(dst + base) = p;
}

// ---------------------------------------------------------------------------
// GEMM: Y[m][n] = sum_k A[m][k] * W[n][k]  (X @ W^T).
// Double-buffered LDS + cross-iteration global_load_lds prefetch, one
// barrier per K-iter. MT x NT tile, BK=32, 256 threads (4 waves, 2x2).
// BF16OUT: Y bf16 scaled by per-z ysc. else: Y fp32 + bias.
// ---------------------------------------------------------------------------
template<int MT, int NT, bool BF16OUT>
__global__ __launch_bounds__(256, 3)
void gemm_xwt(const unsigned short* __restrict__ X0, const unsigned short* __restrict__ X1,
              const unsigned short* __restrict__ X2,
              const unsigned short* __restrict__ W0, const unsigned short* __restrict__ W1,
              const unsigned short* __restrict__ W2,
              void* __restrict__ Y0, void* __restrict__ Y1, void* __restrict__ Y2,
              const float* __restrict__ bias, int M, int N, int K,
              float s0, float s1, float s2)
{
    constexpr int BK = 32;
    constexpr int NI = MT / 32;          // A-frags per wave
    constexpr int NJ = NT / 32;          // B-frags per wave
    // UNPADDED: required by global_load_lds (wave-uniform base + lane*16)
    __shared__ __align__(16) unsigned short As[2][MT * BK];
    __shared__ __align__(16) unsigned short Bs[2][NT * BK];

    const int z = blockIdx.z;
    const unsigned short* __restrict__ X = (z == 0) ? X0 : ((z == 1) ? X1 : X2);
    const unsigned short* __restrict__ W = (z == 0) ? W0 : ((z == 1) ? W1 : W2);
    void* __restrict__ Y                 = (z == 0) ? Y0 : ((z == 1) ? Y1 : Y2);
    const float ysc                      = (z == 0) ? s0 : ((z == 1) ? s1 : s2);

    const int tid  = threadIdx.x;
    const int lane = tid & 63;
    const int wave = tid >> 6;
    const int wm   = (wave >> 1) * (MT / 2);
    const int wn   = (wave & 1) * (NT / 2);
    const int m0   = blockIdx.y * MT;
    const int n0   = blockIdx.x * NT;
    const int l16  = lane & 15;
    const int quad = lane >> 4;

    // async staging: lane i covers row (i>>2), k-chunk (i&3)*8 in a 16-row group
    const int arow = lane >> 2;
    const int akc  = (lane & 3) * 8;

    f32x4 acc[NI][NJ];
    #pragma unroll
    for (int i = 0; i < NI; i++)
        #pragma unroll
        for (int j = 0; j < NJ; j++) acc[i][j] = f32x4{0.f, 0.f, 0.f, 0.f};

    auto stage = [&](int k0, int buf) {
        #pragma unroll
        for (int j = 0; j < NT / 64; j++) {
            const int rr = wave * (NT / 4) + j * 16;
            async_load16(W + (size_t)(n0 + rr + arow) * K + k0 + akc, Bs[buf] + rr * BK);
        }
        #pragma unroll
        for (int j = 0; j < MT / 64; j++) {
            const int rr = wave * (MT / 4) + j * 16;
            async_load16(X + (size_t)(m0 + rr + arow) * K + k0 + akc, As[buf] + rr * BK);
        }
    };

    stage(0, 0);                          // prologue: tile 0 -> buf 0
    const int niter = K / BK;
    for (int i = 0; i < niter; i++) {
        const int cur = i & 1;
        __syncthreads();                  // drains tile-i asyncs (issued 1 phase ago)
        if (i + 1 < niter) stage((i + 1) * BK, cur ^ 1);

        bf16x8 afrag[NI], bfrag[NJ];
        #pragma unroll
        for (int ii = 0; ii < NI; ii++)
            afrag[ii] = *(const bf16x8*)(As[cur] + (wm + ii * 16 + l16) * BK + quad * 8);
        #pragma unroll
        for (int j = 0; j < NJ; j++)
            bfrag[j] = *(const bf16x8*)(Bs[cur] + (wn + j * 16 + l16) * BK + quad * 8);
        #pragma unroll
        for (int ii = 0; ii < NI; ii++)
            #pragma unroll
            for (int j = 0; j < NJ; j++)
                acc[ii][j] = __builtin_amdgcn_mfma_f32_16x16x32_bf16(afrag[ii], bfrag[j], acc[ii][j], 0, 0, 0);
    }

    // Epilogue. C/D layout: col = lane&15, row = quad*4 + reg.
    #pragma unroll
    for (int i = 0; i < NI; i++) {
        #pragma unroll
        for (int j = 0; j < NJ; j++) {
            #pragma unroll
            for (int r = 0; r < 4; r++) {
                const int row = m0 + wm + i * 16 + quad * 4 + r;
                const int col = n0 + wn + j * 16 + l16;
                const float v = acc[i][j][r];
                if (BF16OUT) {
                    ((unsigned short*)Y)[(size_t)row * N + col] = f2bf(v * ysc);
                } else {
                    ((float*)Y)[(size_t)row * N + col] = v + bias[col];
                }
            }
        }
    }
}

// ---------------------------------------------------------------------------
// Mask compaction: softmax weights of masked keys are exactly 0 (exp2(-150)
// underflows), and softmax/PV are permutation-invariant over keys -> drop
// masked columns entirely. ~50% of keys are masked (randint 0..1), halving
// attention work. Order-preserving prefix compaction.
// Grid (32 slot-tiles, 2 batches), 256 threads. Per block:
//   1) block prefix-scan of mask[b] (wave shfl scans + 4-entry combine)
//   2) srcIdx[j] = source key of compacted slot t0+j (-1 = pad, zero-filled)
//   3) gather K rows  Kb -> Kc   (coalesced 2KB row copies)
//   4) gather+transpose V: Vb rows -> LDS tile -> Vtc[(b*EE+e)*SS + slot]
// Tiles with t0 >= nkeep exit (attention never reads them).
// [R13 fix: V-transpose store was uint2 x8 = 32 shorts -- half the 64-slot
//  row; slots 32..63 kept 0xAA poison -> absmax 0.12. Now uint4 x8 = 64.]
// ---------------------------------------------------------------------------
__global__ __launch_bounds__(256, 1)
void compact_kernel(const unsigned short* __restrict__ Kb,
                    const unsigned short* __restrict__ Vb,
                    const int* __restrict__ mask,
                    unsigned short* __restrict__ Kc,
                    unsigned short* __restrict__ Vtc)
{
    constexpr int LDE = 264;                 // 256-e chunk + pad
    __shared__ int srcIdx[64];
    __shared__ int wsum[4];
    __shared__ __align__(16) unsigned short T[64 * LDE];

    const int tid  = threadIdx.x;
    const int lane = tid & 63;
    const int wave = tid >> 6;
    const int b    = blockIdx.y;
    const int t0   = blockIdx.x * 64;

    // per-thread chunk of 8 mask entries
    const int base = tid * 8;
    int v[8]; int run = 0;
    #pragma unroll
    for (int i = 0; i < 8; i++) { v[i] = (mask[b * SS + base + i] != 0) ? 1 : 0; run += v[i]; }

    // wave-inclusive scan of per-thread totals
    int inc = run;
    #pragma unroll
    for (int d = 1; d < 64; d <<= 1) {
        int n = __shfl_up(inc, d, 64);
        if (lane >= d) inc += n;
    }
    if (lane == 63) wsum[wave] = inc;
    __syncthreads();
    const int nkeep = wsum[0] + wsum[1] + wsum[2] + wsum[3];
    if (t0 >= nkeep) return;                 // uniform exit

    if (tid < 64) srcIdx[tid] = -1;
    __syncthreads();

    int r = inc - run;                       // exclusive prefix
    #pragma unroll
    for (int w = 0; w < 4; w++) if (w < wave) r += wsum[w];
    #pragma unroll
    for (int i = 0; i < 8; i++) {
        if (v[i]) {
            if (r >= t0 && r < t0 + 64) srcIdx[r - t0] = base + i;
            r++;
        }
    }
    __syncthreads();

    // K row gather: 64 rows x 2KB, 4 threads/row x 512B
    {
        const int j = tid >> 2, part = tid & 3;
        const int s = srcIdx[j];
        uint4* dst = (uint4*)(Kc + ((size_t)(b * SS + t0 + j)) * EE + part * 256);
        if (s >= 0) {
            const uint4* src = (const uint4*)(Kb + ((size_t)(b * SS + s)) * EE + part * 256);
            #pragma unroll
            for (int c = 0; c < 32; c++) dst[c] = src[c];
        } else {
            #pragma unroll
            for (int c = 0; c < 32; c++) dst[c] = uint4{0, 0, 0, 0};
        }
    }

    // V gather + transpose, 4 chunks of 256 e
    for (int ec = 0; ec < 4; ec++) {
        __syncthreads();
        {
            const int j = tid >> 2, part = tid & 3;
            const int s = srcIdx[j];
            uint4* trow = (uint4*)(T + j * LDE + part * 64);
            if (s >= 0) {
                const uint4* src = (const uint4*)(Vb + ((size_t)(b * SS + s)) * EE + ec * 256 + part * 64);
                #pragma unroll
                for (int c = 0; c < 8; c++) trow[c] = src[c];
            } else {
                #pragma unroll
                for (int c = 0; c < 8; c++) trow[c] = uint4{0, 0, 0, 0};
            }
        }
        __syncthreads();
        {
            const int e = ec * 256 + tid;
            unsigned short* drow = Vtc + ((size_t)(b * EE + e)) * SS + t0;
            unsigned short tmp[64];
            #pragma unroll
            for (int j2 = 0; j2 < 64; j2++) tmp[j2] = T[j2 * LDE + tid];
            #pragma unroll
            for (int c = 0; c < 8; c++) ((uint4*)drow)[c] = ((const uint4*)tmp)[c];  // 8x16B = all 64 slots
        }
    }
}

// ---------------------------------------------------------------------------
// Flash attention v11 = R12's proven kernel (256 thr, 4 waves x 32 q,
// K-tile 64, strides 68, mask-as-C-init->pad-bias, exp2 softmax, register
// prefetch, XCD swizzle) operating on COMPACTED keys: Kc/Vtc hold only the
// ~nkeep unmasked columns; loop runs ceil(nkeep/64) tiles (~17 vs 32).
// nkeep recomputed per block from mask (L2-hot, ~8 loads/thread).
// Pad columns (boundary tile) are zeroed by compact + biased -150 here.
// ---------------------------------------------------------------------------
__global__ __launch_bounds__(256, 2)
void attn_kernel(const unsigned short* __restrict__ Qb,
                 const unsigned short* __restrict__ Kc,
                 const unsigned short* __restrict__ Vtc,
                 const int* __restrict__ mask,
                 unsigned short* __restrict__ AO)
{
    constexpr int LDK = 68;  // conflict-free (measured 0 in R4-R12)
    constexpr int LDV = 68;
    constexpr int LDP = 68;
    __shared__ __align__(16) unsigned short Ks[64 * LDK];       // [key][d]
    __shared__ __align__(16) unsigned short Vs[64 * LDV];       // [d][key]
    __shared__ __align__(16) unsigned short Ps[4 * 32 * LDP];   // per-wave [q(32)][key]
    __shared__ __align__(16) float Msf[64];                     // pad bias (0 / -150)
    __shared__ int nk_s;

    const int tid  = threadIdx.x;
    const int lane = tid & 63;
    const int wave = tid >> 6;
    const int l16  = lane & 15;
    const int quad = lane >> 4;

    // XCD-aware decode (validated R10/R12: FETCH 69.7 -> 12.4 MB)
    const int linear = blockIdx.x;
    const int bh     = (linear & 7) * 4 + ((linear >> 3) & 3);
    const int qblk   = linear >> 5;
    const int b  = bh >> 4;
    const int h  = bh & 15;
    const int q0 = qblk * 128 + wave * 32;

    // recompute nkeep (must match compact_kernel's count)
    if (tid == 0) nk_s = 0;
    __syncthreads();
    {
        int cnt = 0;
        #pragma unroll
        for (int i = 0; i < 8; i++) cnt += (mask[b * SS + tid * 8 + i] != 0) ? 1 : 0;
        #pragma unroll
        for (int d = 32; d >= 1; d >>= 1) cnt += __shfl_xor(cnt, d, 64);
        if (lane == 0) atomicAdd(&nk_s, cnt);
    }
    __syncthreads();
    const int nkeep  = nk_s;
    const int ntiles = (nkeep + 63) >> 6;

    // Q fragments, 2 groups of 16 q (B-operand: lane n=q=l16, k=d=quad*8+j).
    // Pre-scaled by log2e/sqrt(S) in the projection GEMM.
    bf16x8 qf[2][2];
    #pragma unroll
    for (int g = 0; g < 2; g++) {
        const unsigned short* qptr = Qb + (size_t)(b * SS + q0 + g * 16 + l16) * EE + h * DHH;
        qf[g][0] = *(const bf16x8*)(qptr + quad * 8);
        qf[g][1] = *(const bf16x8*)(qptr + 32 + quad * 8);
    }

    float lsum[2] = {0.f, 0.f};
    f32x4 o_acc[2][4];
    #pragma unroll
    for (int g = 0; g < 2; g++)
        #pragma unroll
        for (int j = 0; j < 4; j++) o_acc[g][j] = f32x4{0.f, 0.f, 0.f, 0.f};

    unsigned short* Pw = Ps + wave * 32 * LDP;

    // staging: 4 threads per row, 32B each
    const int srow = tid >> 2;          // 0..63
    const int sc   = (tid & 3) * 16;    // elem offset 0,16,32,48

    // ---- register prefetch state (tile t+1 lives here during compute of t)
    uint4 kr0, kr1, vr0, vr1;
    auto gload = [&](int t0) {
        const unsigned short* kg = Kc + (size_t)(b * SS + t0 + srow) * EE + h * DHH + sc;
        kr0 = *(const uint4*)(kg);
        kr1 = *(const uint4*)(kg + 8);
        const unsigned short* vg = Vtc + (size_t)(b * EE + h * DHH + srow) * SS + t0 + sc;
        vr0 = *(const uint4*)(vg);
        vr1 = *(const uint4*)(vg + 8);
    };
    gload(0);

    for (int it = 0; it < ntiles; it++) {
        const int t0 = it * 64;
        __syncthreads();   // prior iteration's Ks/Vs frag reads done
        *(uint4*)(Ks + srow * LDK + sc)     = kr0;
        *(uint4*)(Ks + srow * LDK + sc + 8) = kr1;
        *(uint4*)(Vs + srow * LDV + sc)     = vr0;
        *(uint4*)(Vs + srow * LDV + sc + 8) = vr1;
        if (tid < 64) Msf[tid] = (t0 + tid < nkeep) ? 0.0f : -150.0f;
        __syncthreads();

        // prefetch next tile into registers, overlapped with compute below
        if (it + 1 < ntiles) gload(t0 + 64);

        // S^T tile (64 keys x 32 q): pad bias as MFMA C-init, p = exp2(score).
        #pragma unroll
        for (int nt = 0; nt < 4; nt++) {
            bf16x8 kf0 = *(const bf16x8*)(Ks + (nt * 16 + l16) * LDK + quad * 8);
            bf16x8 kf1 = *(const bf16x8*)(Ks + (nt * 16 + l16) * LDK + 32 + quad * 8);
            const f32x4 cinit = *(const f32x4*)(Msf + nt * 16 + quad * 4);
            #pragma unroll
            for (int g = 0; g < 2; g++) {
                f32x4 a = __builtin_amdgcn_mfma_f32_16x16x32_bf16(kf0, qf[g][0], cinit, 0, 0, 0);
                a = __builtin_amdgcn_mfma_f32_16x16x32_bf16(kf1, qf[g][1], a, 0, 0, 0);
                const float p0 = EXP2(a[0]);
                const float p1 = EXP2(a[1]);
                const float p2 = EXP2(a[2]);
                const float p3 = EXP2(a[3]);
                lsum[g] += (p0 + p1) + (p2 + p3);
                uint2 pck;
                pck.x = pk2bf(p0, p1);
                pck.y = pk2bf(p2, p3);
                *(uint2*)(Pw + (g * 16 + l16) * LDP + nt * 16 + quad * 4) = pck;
            }
        }

        // wave-local: ensure P writes land before P frag reads (no barrier)
        __builtin_amdgcn_s_waitcnt(0xC07F);   // lgkmcnt(0)

        // O^T += V^T . P  — each vf read feeds both q-groups
        #pragma unroll
        for (int s2 = 0; s2 < 2; s2++) {
            bf16x8 pf0 = *(const bf16x8*)(Pw + l16 * LDP + s2 * 32 + quad * 8);
            bf16x8 pf1 = *(const bf16x8*)(Pw + (16 + l16) * LDP + s2 * 32 + quad * 8);
            #pragma unroll
            for (int jg = 0; jg < 4; jg++) {
                bf16x8 vf = *(const bf16x8*)(Vs + (jg * 16 + l16) * LDV + s2 * 32 + quad * 8);
                o_acc[0][jg] = __builtin_amdgcn_mfma_f32_16x16x32_bf16(vf, pf0, o_acc[0][jg], 0, 0, 0);
                o_acc[1][jg] = __builtin_amdgcn_mfma_f32_16x16x32_bf16(vf, pf1, o_acc[1][jg], 0, 0, 0);
            }
        }
    }

    // final l reduction + store, per q-group
    #pragma unroll
    for (int g = 0; g < 2; g++) {
        float ls = lsum[g];
        ls += __shfl_xor(ls, 16, 64);
        ls += __shfl_xor(ls, 32, 64);
        const float rl = 1.0f / ls;
        const size_t orow = (size_t)(b * SS + q0 + g * 16 + l16) * EE + h * DHH;
        #pragma unroll
        for (int jg = 0; jg < 4; jg++) {
            uint2 pck;
            pck.x = pk2bf(o_acc[g][jg][0] * rl, o_acc[g][jg][1] * rl);
            pck.y = pk2bf(o_acc[g][jg][2] * rl, o_acc[g][jg][3] * rl);
            *(uint2*)(AO + orow + jg * 16 + quad * 4) = pck;
        }
    }
}

// ---------------------------------------------------------------------------
// Aliasing plan (stream order makes every alias race-free):
//   d_out (16 MB): phase1 [Xq 8MB | Xk 8MB] (dead after proj GEMM);
//                  phase2 [Kc 8MB | Vtc 8MB] (compacted K / V^T, dead after
//                  attn); phase3 final GEMM overwrites with the real output.
//   ws (40 MB):    [Wb 8MB | Xv 8MB | Qb 8MB | Kb 8MB | Vb 8MB]
//                  AOb aliases Xv (Xv dead once proj GEMM reads it).
// ---------------------------------------------------------------------------
extern "C" void kernel_launch(void* const* d_in, const int* in_sizes, int n_in,
                              void* d_out, int out_size, void* d_ws, size_t ws_size,
                              hipStream_t stream)
{
    (void)in_sizes; (void)n_in; (void)out_size; (void)ws_size;
    const float* queries = (const float*)d_in[0];
    const float* keys    = (const float*)d_in[1];
    const float* values  = (const float*)d_in[2];
    const int*   mask    = (const int*)d_in[3];
    const float* Wq      = (const float*)d_in[4];
    const float* Wk      = (const float*)d_in[5];
    const float* Wv      = (const float*)d_in[6];
    const float* Wo      = (const float*)d_in[7];
    const float* bo      = (const float*)d_in[8];

    const size_t NE = (size_t)BB * SS * EE;          // 4.19M elements
    const size_t WE = (size_t)EE * EE;               // 1.05M elements

    unsigned short* Xq  = (unsigned short*)d_out;    // 8 MB (scratch phase)
    unsigned short* Xk  = Xq + NE;                   // 8 MB (scratch phase)
    unsigned short* Kc  = (unsigned short*)d_out;    // compacted K (after proj)
    unsigned short* Vtc = Kc + NE;                   // compacted V^T
    unsigned short* Wb  = (unsigned short*)d_ws;     // 8 MB (4 weights bf16)
    unsigned short* Xv  = Wb + 4 * WE;               // 8 MB
    unsigned short* Qb  = Xv + NE;                   // 8 MB (pre-scaled)
    unsigned short* Kb  = Qb + NE;                   // 8 MB
    unsigned short* Vb  = Kb + NE;                   // 8 MB (V rows)
    unsigned short* AOb = Xv;                        // alias: Xv dead after proj GEMM

    const int M = BB * SS, N = EE, K = EE;
    // 1/sqrt(2048) * log2(e): softmax exp computed as exp2 of pre-scaled score
    const float qscale = 0.022097086912079608f * 1.4426950408889634f;

    cvt_kernel<<<dim3(2048, 7), 256, 0, stream>>>(
        Wq, Wk, Wv, Wo, queries, keys, values, Wb, Xq, Xk, Xv);

    dim3 gproj(N / 128, M / 128, 3);
    gemm_xwt<128, 128, true><<<gproj, 256, 0, stream>>>(
        Xq, Xk, Xv, Wb, Wb + WE, Wb + 2 * WE,
        (void*)Qb, (void*)Kb, (void*)Vb, nullptr, M, N, K,
        qscale, 1.0f, 1.0f);

    compact_kernel<<<dim3(SS / 64, BB), 256, 0, stream>>>(Kb, Vb, mask, Kc, Vtc);

    attn_kernel<<<dim3(512), 256, 0, stream>>>(Qb, Kc, Vtc, mask, AOb);

    dim3 gout(N / 64, M / 64, 1);
    gemm_xwt<64, 64, false><<<gout, 256, 0, stream>>>(
        AOb, AOb, AOb, Wb + 3 * WE, Wb + 3 * WE, Wb + 3 * WE,
        d_out, d_out, d_out, bo, M, N, K, 1.0f, 1.0f, 1.0f);
}